// Round 5
// baseline (36.399 us; speedup 1.0000x reference)
//
#include <hip/hip_runtime.h>
#include <math.h>

#define TT 16
#define HH 48
#define WW 48
#define CC 64
#define DD 6
#define VS (TT*HH*WW)     // 36864 voxels
#define SS (HH*WW)        // 2304 queries
#define NT (VS/16)        // 2304 voxel-tiles of 16
#define QW 64             // queries per attn wave (4 fragments of 16)
#define NFR 4             // Q fragments per wave
#define NQG (SS/QW)       // 36 query groups
#define NCH 128           // voxel chunks
#define TPC (NT/NCH)      // 18 tiles per chunk
#define LOG2E 1.44269504088896f

typedef float  f4 __attribute__((ext_vector_type(4)));
typedef float  f2 __attribute__((ext_vector_type(2)));
typedef _Float16 h4 __attribute__((ext_vector_type(4)));
typedef _Float16 h2 __attribute__((ext_vector_type(2)));

// ---------------- Kernel A: projection + LN + fragment packing ----------------
// Blocks 0..143: voxels (K). Pack per 16-voxel tile the exact MFMA fragment
// layout: lane L = r + 16g;  K half4 (A-frag MFMA1) = features g*4+j of voxel r;
// G half4 (B-frag MFMA2) = coord c=r of voxels g*4+j (ct,ch,cw,1; 0 for r>=4).
// Stored as one float4 per lane: [K halfs | G halfs].
// Blocks 144..152: queries. LN'd, pre-scaled by log2(e), slots 6,7 = 0.
__global__ __launch_bounds__(256) void proj_kernel(
    const float* __restrict__ vol, const float* __restrict__ slc,
    const float* __restrict__ w2d, const float* __restrict__ b2d,
    const float* __restrict__ g2d, const float* __restrict__ be2d,
    const float* __restrict__ w3d, const float* __restrict__ b3d,
    const float* __restrict__ g3d, const float* __restrict__ be3d,
    f4* __restrict__ Kf, float* __restrict__ Qp)
{
    int tid = threadIdx.x;
    int gid = blockIdx.x * 256 + tid;
    __shared__ float sk[256][7];   // pad to 7: 2-way bank alias only (free)

    bool isK = gid < VS;
    const float *src, *wgt, *bia, *gam, *bet;
    int pos, stride;
    if (isK) { src = vol; wgt = w3d; bia = b3d; gam = g3d; bet = be3d; pos = gid;      stride = VS; }
    else     { src = slc; wgt = w2d; bia = b2d; gam = g2d; bet = be2d; pos = gid - VS; stride = SS; }

    float y[DD];
    {
        float acc[DD] = {0.f,0.f,0.f,0.f,0.f,0.f};
        #pragma unroll
        for (int c = 0; c < CC; ++c) {
            float x = src[c * stride + pos];
            #pragma unroll
            for (int d = 0; d < DD; ++d) acc[d] = fmaf(wgt[d*CC + c], x, acc[d]);
        }
        float mu = 0.f;
        #pragma unroll
        for (int d = 0; d < DD; ++d) { acc[d] += bia[d]; mu += acc[d]; }
        mu *= (1.f/DD);
        float var = 0.f;
        #pragma unroll
        for (int d = 0; d < DD; ++d) { float t = acc[d] - mu; var = fmaf(t, t, var); }
        var *= (1.f/DD);
        float inv = rsqrtf(var + 1e-5f);
        #pragma unroll
        for (int d = 0; d < DD; ++d) y[d] = (acc[d] - mu) * inv * gam[d] + bet[d];
    }

    if (isK) {
        #pragma unroll
        for (int d = 0; d < DD; ++d) sk[tid][d] = y[d];
        __syncthreads();

        int tl = tid >> 4;              // tile within block (16 tiles)
        int r  = tid & 15;
        int tileg = blockIdx.x * 16 + tl;
        #pragma unroll
        for (int g = 0; g < 4; ++g) {
            h4 kh = (h4){0,0,0,0};
            if (g == 0) {
                kh = (h4){ (_Float16)sk[tl*16+r][0], (_Float16)sk[tl*16+r][1],
                           (_Float16)sk[tl*16+r][2], (_Float16)sk[tl*16+r][3] };
            } else if (g == 1) {
                kh = (h4){ (_Float16)sk[tl*16+r][4], (_Float16)sk[tl*16+r][5],
                           (_Float16)0.f, (_Float16)0.f };
            }
            h4 gh = (h4){0,0,0,0};
            if (r < 4) {
                #pragma unroll
                for (int j = 0; j < 4; ++j) {
                    int v   = tileg*16 + g*4 + j;
                    int t   = v / (HH*WW);
                    int rem = v - t*(HH*WW);
                    int h   = rem / WW;
                    int w   = rem - h*WW;
                    float val = (r==0) ? (float)t - 7.5f
                              : (r==1) ? (float)h - 23.5f
                              : (r==2) ? (float)w - 23.5f
                              :          1.0f;
                    gh[j] = (_Float16)val;
                }
            }
            f2 kl = __builtin_bit_cast(f2, kh);
            f2 gl = __builtin_bit_cast(f2, gh);
            f4 o = (f4){kl.x, kl.y, gl.x, gl.y};
            Kf[tileg*64 + r + 16*g] = o;
        }
    } else {
        #pragma unroll
        for (int d = 0; d < DD; ++d) Qp[pos*8 + d] = y[d] * LOG2E;
        Qp[pos*8 + 6] = 0.f;
        Qp[pos*8 + 7] = 0.f;
    }
}

// ---------------- Kernel B: MFMA attention ----------------
// One wave per block; wave holds 4 Q-fragments (64 queries) and streams 18
// K/G tile lines (its chunk) with explicit next-line prefetch. 4608 waves
// (4.5/SIMD) restore latency hiding; each 1KB line feeds 4x(MFMA1->exp->MFMA2).
__global__ __launch_bounds__(64, 8) void attn_kernel(
    const f4* __restrict__ Kf, const float* __restrict__ Qp,
    float* __restrict__ Pc)
{
    int lane = threadIdx.x;
    int g = lane >> 4, r = lane & 15;
    int qg = blockIdx.x >> 7;          // / NCH
    int ch = blockIdx.x & (NCH-1);
    int qbase = qg*QW;

    // B-frags of MFMA1: lane holds Q[query=r (+16f)][features g*4+j] (0 for g>=2)
    h4 qf[NFR];
    #pragma unroll
    for (int f = 0; f < NFR; ++f) {
        qf[f] = (h4){0,0,0,0};
        if (g < 2) {
            f4 qv = *(const f4*)(Qp + (qbase + f*16 + r)*8 + g*4);
            qf[f] = (h4){ (_Float16)qv.x, (_Float16)qv.y, (_Float16)qv.z, (_Float16)qv.w };
        }
    }

    f4 z = (f4){0,0,0,0};
    f4 out[NFR];
    #pragma unroll
    for (int f = 0; f < NFR; ++f) out[f] = z;

    const f4* kp = Kf + (ch*TPC)*64 + lane;
    f4 v = kp[0];                       // prefetched current line
    for (int it = 0; it < TPC; ++it) {
        f4 vn;
        if (it + 1 < TPC) vn = kp[(it+1)*64];   // issue next load before compute
        h4 ka = __builtin_bit_cast(h4, (f2){v.x, v.y});
        h4 ga = __builtin_bit_cast(h4, (f2){v.z, v.w});
        #pragma unroll
        for (int f = 0; f < NFR; ++f) {
            // logits: D[voxel][query]; lane gets query=r, voxels g*4+reg
            f4 s = __builtin_amdgcn_mfma_f32_16x16x16f16(ka, qf[f], z, 0, 0, 0);
            float p0 = __builtin_amdgcn_exp2f(s.x);
            float p1 = __builtin_amdgcn_exp2f(s.y);
            float p2 = __builtin_amdgcn_exp2f(s.z);
            float p3 = __builtin_amdgcn_exp2f(s.w);
            h2 pl = __builtin_bit_cast(h2, __builtin_amdgcn_cvt_pkrtz(p0, p1));
            h2 ph = __builtin_bit_cast(h2, __builtin_amdgcn_cvt_pkrtz(p2, p3));
            h4 pf = (h4){pl.x, pl.y, ph.x, ph.y};   // A-frag MFMA2: row=query=r, k=voxel g*4+j
            out[f] = __builtin_amdgcn_mfma_f32_16x16x16f16(pf, ga, out[f], 0, 0, 0);
        }
        v = vn;
    }
    // out[f]: lane holds queries f*16 + g*4+reg at column c=r (c<4: ct,ch,cw,sum)
    if (r < 4) {
        #pragma unroll
        for (int f = 0; f < NFR; ++f)
            #pragma unroll
            for (int j = 0; j < 4; ++j) {
                int q = qbase + f*16 + g*4 + j;
                Pc[(ch*SS + q)*4 + r] = out[f][j];
            }
    }
}

// ---------------- Kernel C: merge chunks, finalize flow ----------------
__global__ __launch_bounds__(256) void final_kernel(
    const f4* __restrict__ Pc, float* __restrict__ out)
{
    int q = blockIdx.x * 256 + threadIdx.x;
    if (q >= SS) return;
    f4 a = (f4){0,0,0,0};
    #pragma unroll 8
    for (int c = 0; c < NCH; ++c) a += Pc[c*SS + q];
    float inv = 1.f / a.w;
    int h = q / WW;
    int w = q - h*WW;
    out[q]        = a.x * inv;                        // t-channel (slice t grid = 0)
    out[SS + q]   = a.y * inv - ((float)h - 23.5f);   // h-channel
    out[2*SS + q] = a.z * inv - ((float)w - 23.5f);   // w-channel
}

extern "C" void kernel_launch(void* const* d_in, const int* in_sizes, int n_in,
                              void* d_out, int out_size, void* d_ws, size_t ws_size,
                              hipStream_t stream)
{
    const float* vol  = (const float*)d_in[0];
    const float* slc  = (const float*)d_in[1];
    const float* w2d  = (const float*)d_in[2];
    const float* b2d  = (const float*)d_in[3];
    const float* g2d  = (const float*)d_in[4];
    const float* be2d = (const float*)d_in[5];
    const float* w3d  = (const float*)d_in[6];
    const float* b3d  = (const float*)d_in[7];
    const float* g3d  = (const float*)d_in[8];
    const float* be3d = (const float*)d_in[9];
    float* out = (float*)d_out;

    // workspace: Kf (2.36MB) | Qp (73.7KB) | Pc (NCH*SS*16B = 4.72MB)
    f4*    Kf = (f4*)d_ws;
    float* Qp = (float*)(Kf + NT*64);
    f4*    Pc = (f4*)(Qp + SS*8);

    proj_kernel<<<(VS + SS)/256, 256, 0, stream>>>(vol, slc, w2d, b2d, g2d, be2d,
                                                   w3d, b3d, g3d, be3d, Kf, Qp);
    attn_kernel<<<NQG*NCH, 64, 0, stream>>>(Kf, Qp, (float*)Pc);
    final_kernel<<<(SS + 255)/256, 256, 0, stream>>>(Pc, out);
}

// Round 6
// 33.650 us; speedup vs baseline: 1.0817x; 1.0817x over previous
//
#include <hip/hip_runtime.h>
#include <math.h>

#define TT 16
#define HH 48
#define WW 48
#define CC 64
#define DD 6
#define VS (TT*HH*WW)     // 36864 voxels
#define SS (HH*WW)        // 2304 queries
#define NT (VS/16)        // 2304 voxel-tiles of 16
#define NFR 4             // Q fragments per wave (64 queries/wave)
#define NQB (SS/256)      // 9 query blocks (256 queries per block)
#define NCH 256           // voxel chunks
#define TPC (NT/NCH)      // 9 tiles per chunk
#define LOG2E 1.44269504088896f

typedef float  f4 __attribute__((ext_vector_type(4)));
typedef float  f2 __attribute__((ext_vector_type(2)));
typedef _Float16 h4 __attribute__((ext_vector_type(4)));
typedef _Float16 h2 __attribute__((ext_vector_type(2)));

// ---------------- Kernel A: projection + LN + fragment packing ----------------
// Blocks 0..143: voxels (K). Pack per 16-voxel tile the exact MFMA fragment
// layout: lane L = r + 16g;  K half4 (A-frag MFMA1) = features g*4+j of voxel r;
// G half4 (B-frag MFMA2) = coord c=r of voxels g*4+j (ct,ch,cw,1; 0 for r>=4).
// Stored as one float4 per lane: [K halfs | G halfs].
// Blocks 144..152: queries. LN'd, pre-scaled by log2(e), slots 6,7 = 0.
__global__ __launch_bounds__(256) void proj_kernel(
    const float* __restrict__ vol, const float* __restrict__ slc,
    const float* __restrict__ w2d, const float* __restrict__ b2d,
    const float* __restrict__ g2d, const float* __restrict__ be2d,
    const float* __restrict__ w3d, const float* __restrict__ b3d,
    const float* __restrict__ g3d, const float* __restrict__ be3d,
    f4* __restrict__ Kf, float* __restrict__ Qp)
{
    int tid = threadIdx.x;
    int gid = blockIdx.x * 256 + tid;
    __shared__ float sk[256][7];   // pad to 7: 2-way bank alias only (free)

    bool isK = gid < VS;
    const float *src, *wgt, *bia, *gam, *bet;
    int pos, stride;
    if (isK) { src = vol; wgt = w3d; bia = b3d; gam = g3d; bet = be3d; pos = gid;      stride = VS; }
    else     { src = slc; wgt = w2d; bia = b2d; gam = g2d; bet = be2d; pos = gid - VS; stride = SS; }

    float y[DD];
    {
        float acc[DD] = {0.f,0.f,0.f,0.f,0.f,0.f};
        for (int c = 0; c < CC; ++c) {           // no forced unroll (R4 regression suspect)
            float x = src[c * stride + pos];
            #pragma unroll
            for (int d = 0; d < DD; ++d) acc[d] = fmaf(wgt[d*CC + c], x, acc[d]);
        }
        float mu = 0.f;
        #pragma unroll
        for (int d = 0; d < DD; ++d) { acc[d] += bia[d]; mu += acc[d]; }
        mu *= (1.f/DD);
        float var = 0.f;
        #pragma unroll
        for (int d = 0; d < DD; ++d) { float t = acc[d] - mu; var = fmaf(t, t, var); }
        var *= (1.f/DD);
        float inv = rsqrtf(var + 1e-5f);
        #pragma unroll
        for (int d = 0; d < DD; ++d) y[d] = (acc[d] - mu) * inv * gam[d] + bet[d];
    }

    if (isK) {
        #pragma unroll
        for (int d = 0; d < DD; ++d) sk[tid][d] = y[d];
        __syncthreads();

        int tl = tid >> 4;              // tile within block (16 tiles)
        int r  = tid & 15;
        int tileg = blockIdx.x * 16 + tl;
        #pragma unroll
        for (int g = 0; g < 4; ++g) {
            h4 kh = (h4){0,0,0,0};
            if (g == 0) {
                kh = (h4){ (_Float16)sk[tl*16+r][0], (_Float16)sk[tl*16+r][1],
                           (_Float16)sk[tl*16+r][2], (_Float16)sk[tl*16+r][3] };
            } else if (g == 1) {
                kh = (h4){ (_Float16)sk[tl*16+r][4], (_Float16)sk[tl*16+r][5],
                           (_Float16)0.f, (_Float16)0.f };
            }
            h4 gh = (h4){0,0,0,0};
            if (r < 4) {
                #pragma unroll
                for (int j = 0; j < 4; ++j) {
                    int v   = tileg*16 + g*4 + j;
                    int t   = v / (HH*WW);
                    int rem = v - t*(HH*WW);
                    int h   = rem / WW;
                    int w   = rem - h*WW;
                    float val = (r==0) ? (float)t - 7.5f
                              : (r==1) ? (float)h - 23.5f
                              : (r==2) ? (float)w - 23.5f
                              :          1.0f;
                    gh[j] = (_Float16)val;
                }
            }
            f2 kl = __builtin_bit_cast(f2, kh);
            f2 gl = __builtin_bit_cast(f2, gh);
            f4 o = (f4){kl.x, kl.y, gl.x, gl.y};
            Kf[tileg*64 + r + 16*g] = o;
        }
    } else {
        #pragma unroll
        for (int d = 0; d < DD; ++d) Qp[pos*8 + d] = y[d] * LOG2E;
        Qp[pos*8 + 6] = 0.f;
        Qp[pos*8 + 7] = 0.f;
    }
}

// ---------------- Kernel B: MFMA attention ----------------
// Block = 4 waves x 256 threads; wave holds 4 Q-fragments (64 queries) and
// streams 9 K/G tile lines (its chunk) with rotated prefetch. 9216 waves
// (~24-32/CU) for latency hiding; each 1KB line feeds 4x(MFMA1->exp->MFMA2).
// Pc layout transposed: Pc[q][ch] so the merge reads coalesced.
__global__ __launch_bounds__(256, 6) void attn_kernel(
    const f4* __restrict__ Kf, const float* __restrict__ Qp,
    float* __restrict__ Pc)
{
    int tid  = threadIdx.x;
    int wv   = tid >> 6;
    int lane = tid & 63;
    int g = lane >> 4, r = lane & 15;
    int qb = blockIdx.x >> 8;          // / NCH
    int ch = blockIdx.x & (NCH-1);
    int qbase = qb*256 + wv*64;

    // B-frags of MFMA1: lane holds Q[query=r (+16f)][features g*4+j] (0 for g>=2)
    h4 qf[NFR];
    #pragma unroll
    for (int f = 0; f < NFR; ++f) {
        qf[f] = (h4){0,0,0,0};
        if (g < 2) {
            f4 qv = *(const f4*)(Qp + (qbase + f*16 + r)*8 + g*4);
            qf[f] = (h4){ (_Float16)qv.x, (_Float16)qv.y, (_Float16)qv.z, (_Float16)qv.w };
        }
    }

    f4 z = (f4){0,0,0,0};
    f4 out[NFR];
    #pragma unroll
    for (int f = 0; f < NFR; ++f) out[f] = z;

    const f4* kp = Kf + (ch*TPC)*64 + lane;
    f4 v = kp[0];                       // prefetched current line
    #pragma unroll
    for (int it = 0; it < TPC; ++it) {
        f4 vn;
        if (it + 1 < TPC) vn = kp[(it+1)*64];   // next line in flight over compute
        h4 ka = __builtin_bit_cast(h4, (f2){v.x, v.y});
        h4 ga = __builtin_bit_cast(h4, (f2){v.z, v.w});
        #pragma unroll
        for (int f = 0; f < NFR; ++f) {
            // logits: D[voxel][query]; lane gets query=r, voxels g*4+reg
            f4 s = __builtin_amdgcn_mfma_f32_16x16x16f16(ka, qf[f], z, 0, 0, 0);
            float p0 = __builtin_amdgcn_exp2f(s.x);
            float p1 = __builtin_amdgcn_exp2f(s.y);
            float p2 = __builtin_amdgcn_exp2f(s.z);
            float p3 = __builtin_amdgcn_exp2f(s.w);
            h2 pl = __builtin_bit_cast(h2, __builtin_amdgcn_cvt_pkrtz(p0, p1));
            h2 ph = __builtin_bit_cast(h2, __builtin_amdgcn_cvt_pkrtz(p2, p3));
            h4 pf = (h4){pl.x, pl.y, ph.x, ph.y};   // A-frag MFMA2: row=query=r, k=voxel g*4+j
            out[f] = __builtin_amdgcn_mfma_f32_16x16x16f16(pf, ga, out[f], 0, 0, 0);
        }
        v = vn;
    }
    // out[f]: lane holds queries f*16 + g*4+reg at column c=r (c<4: ct,ch,cw,sum)
    if (r < 4) {
        #pragma unroll
        for (int f = 0; f < NFR; ++f)
            #pragma unroll
            for (int j = 0; j < 4; ++j) {
                int q = qbase + f*16 + g*4 + j;
                Pc[(q*NCH + ch)*4 + r] = out[f][j];
            }
    }
}

// ---------------- Kernel C: merge chunks, finalize flow ----------------
// One wave per query: lane sums 4 f4 partials (coalesced, Pc[q][ch] layout),
// butterfly-reduce across 64 lanes, lane 0 writes the 3 flow channels.
__global__ __launch_bounds__(256) void final_kernel(
    const f4* __restrict__ Pc, float* __restrict__ out)
{
    int wv   = threadIdx.x >> 6;
    int lane = threadIdx.x & 63;
    int q = blockIdx.x * 4 + wv;

    f4 a = (f4){0,0,0,0};
    #pragma unroll
    for (int i = 0; i < NCH/64; ++i) a += Pc[q*NCH + i*64 + lane];

    #pragma unroll
    for (int off = 32; off >= 1; off >>= 1) {
        a.x += __shfl_xor(a.x, off);
        a.y += __shfl_xor(a.y, off);
        a.z += __shfl_xor(a.z, off);
        a.w += __shfl_xor(a.w, off);
    }
    if (lane == 0) {
        float inv = 1.f / a.w;
        int h = q / WW;
        int w = q - h*WW;
        out[q]        = a.x * inv;                        // t-channel (slice t grid = 0)
        out[SS + q]   = a.y * inv - ((float)h - 23.5f);   // h-channel
        out[2*SS + q] = a.z * inv - ((float)w - 23.5f);   // w-channel
    }
}

extern "C" void kernel_launch(void* const* d_in, const int* in_sizes, int n_in,
                              void* d_out, int out_size, void* d_ws, size_t ws_size,
                              hipStream_t stream)
{
    const float* vol  = (const float*)d_in[0];
    const float* slc  = (const float*)d_in[1];
    const float* w2d  = (const float*)d_in[2];
    const float* b2d  = (const float*)d_in[3];
    const float* g2d  = (const float*)d_in[4];
    const float* be2d = (const float*)d_in[5];
    const float* w3d  = (const float*)d_in[6];
    const float* b3d  = (const float*)d_in[7];
    const float* g3d  = (const float*)d_in[8];
    const float* be3d = (const float*)d_in[9];
    float* out = (float*)d_out;

    // workspace: Kf (2.36MB) | Qp (73.7KB) | Pc (SS*NCH*16B = 9.44MB)
    f4*    Kf = (f4*)d_ws;
    float* Qp = (float*)(Kf + NT*64);
    f4*    Pc = (f4*)(Qp + SS*8);

    proj_kernel<<<(VS + SS)/256, 256, 0, stream>>>(vol, slc, w2d, b2d, g2d, be2d,
                                                   w3d, b3d, g3d, be3d, Kf, Qp);
    attn_kernel<<<NQB*NCH, 256, 0, stream>>>(Kf, Qp, (float*)Pc);
    final_kernel<<<SS/4, 256, 0, stream>>>(Pc, out);
}